// Round 6
// baseline (396.507 us; speedup 1.0000x reference)
//
#include <hip/hip_runtime.h>
#include <hip/hip_bf16.h>
#include <math.h>

#define B_ 16
#define C_ 256
#define H_ 128
#define W_ 512
#define AF_ 256
#define HS_ 256

typedef float f4v __attribute__((ext_vector_type(4)));

// ---------------- L1: pre (w2 transpose + hv) fused with pool.
// bid 0..255   : transpose convd_w (f,c,t) -> w2[(c*5+t)*256 + f]
// bid 256..271 : hv[b,f] = hidden[0,0,b,:] @ hid_w + hid_b
// bid 272..    : adaptive max pool (win=4) + dot dw_w -> h_feat[b,c,h]
//                one wave per row of 512 floats (measured best: multi-row
//                per wave regressed R2 +47us / R3 +19us). nt loads: feat is
//                streaming, no reuse (L3 retention measured ~nil in R4).
__global__ void k_pre_pool(const float* __restrict__ feat,
                           const float* __restrict__ dw_w,
                           const float* __restrict__ dw_b,
                           const float* __restrict__ convd_w,
                           const float* __restrict__ hidden,
                           const float* __restrict__ hid_w,
                           const float* __restrict__ hid_b,
                           float* __restrict__ hf, float* __restrict__ w2,
                           float* __restrict__ hv) {
  int bid = blockIdx.x, tid = threadIdx.x;
  if (bid < 256) {
    int f = bid;
#pragma unroll
    for (int q = 0; q < 5; ++q) {
      int r = q * 256 + tid;  // 0..1279 = c*5+t
      w2[(size_t)r * 256 + f] = convd_w[(size_t)f * 1280 + r];
    }
  } else if (bid < 272) {
    int b = bid - 256;
    const float* hh = hidden + b * HS_;
    float acc = hid_b[tid];
    for (int k = 0; k < HS_; ++k) acc = fmaf(hh[k], hid_w[k * AF_ + tid], acc);
    hv[b * AF_ + tid] = acc;
  } else {
    int wid = (bid - 272) * 4 + (tid >> 6);   // row id, 524288 rows
    int lane = tid & 63;
    const f4v* row = reinterpret_cast<const f4v*>(feat) + (size_t)wid * 128;
    f4v a = __builtin_nontemporal_load(row + lane);
    f4v b = __builtin_nontemporal_load(row + lane + 64);
    float m0 = fmaxf(fmaxf(a.x, a.y), fmaxf(a.z, a.w));
    float m1 = fmaxf(fmaxf(b.x, b.y), fmaxf(b.z, b.w));
    float p = m0 * dw_w[lane] + m1 * dw_w[lane + 64];
#pragma unroll
    for (int off = 32; off > 0; off >>= 1) p += __shfl_down(p, off, 64);
    if (lane == 0) hf[wid] = p + dw_b[0];
  }
}

// ---------------- L2: build s (tanh'd) + align. grid = B*(H/4), block 256 (f)
__global__ void k_sbuild(const float* __restrict__ pa,
                         const float* __restrict__ cv,
                         const float* __restrict__ hf,
                         const float* __restrict__ enc_w, const float* __restrict__ enc_b,
                         const float* __restrict__ conv_w, const float* __restrict__ conv_b,
                         const float* __restrict__ dcb_w, const float* __restrict__ dcb_b,
                         const float* __restrict__ hv,
                         const float* __restrict__ align_w, const float* __restrict__ align_b,
                         float* __restrict__ sbuf, float* __restrict__ alignv) {
  __shared__ float cat[2][H_];
  __shared__ float stats[4];     // mu0, inv_sigma0, mu1, inv_sigma1
  __shared__ float cbl[4][16];
  __shared__ float red[4][4];    // [wave][j]
  int bidx = blockIdx.x;
  int b = bidx >> 5;
  int h0 = (bidx & 31) * 4;
  int tid = threadIdx.x;

  if (tid < H_) {
    cat[0][tid] = pa[b * H_ + tid];
    float x = cv[b * H_ + tid];
    cat[1][tid] = fminf(fmaxf(x, 0.f), 1.f);
  }
  __syncthreads();
  if (tid < 2) {
    float s = 0.f, s2 = 0.f;
    for (int t = 0; t < H_; ++t) { float x = cat[tid][t]; s += x; s2 += x * x; }
    float mu = s / (float)H_;
    float var = s2 / (float)H_ - mu * mu;
    stats[tid * 2] = mu;
    stats[tid * 2 + 1] = rsqrtf(var + 1e-5f);
  }
  __syncthreads();
  {
    int ch = tid >> 7, t = tid & 127;     // all 256 threads
    cat[ch][t] = (cat[ch][t] - stats[ch * 2]) * stats[ch * 2 + 1];
  }
  __syncthreads();
  if (tid < 64) {            // cb[k, h0+j], kernel 15, pad 7
    int k = tid & 15, j = tid >> 4;
    int h = h0 + j;
    float acc = conv_b[k];
    for (int c2 = 0; c2 < 2; ++c2)
      for (int t = 0; t < 15; ++t) {
        int hh = h + t - 7;
        if (hh >= 0 && hh < H_) acc += cat[c2][hh] * conv_w[(k * 2 + c2) * 15 + t];
      }
    cbl[j][k] = acc;
  }
  __syncthreads();

  int f = tid;
  float base = enc_b[f] + dcb_b[f] + hv[b * AF_ + f];
  float acc[4];
#pragma unroll
  for (int j = 0; j < 4; ++j) {
    float a = base;
#pragma unroll
    for (int k = 0; k < 16; ++k) a = fmaf(cbl[j][k], dcb_w[k * AF_ + f], a);
    acc[j] = a;
  }
  const float* hfb = hf + (size_t)(b * C_) * H_ + h0;   // wave-uniform scalar loads
  for (int c = 0; c < C_; ++c) {
    float w = enc_w[c * AF_ + f];
#pragma unroll
    for (int j = 0; j < 4; ++j) acc[j] = fmaf(hfb[c * H_ + j], w, acc[j]);
  }
  float aw = align_w[f];
  int wvi = tid >> 6, lane = tid & 63;
#pragma unroll
  for (int j = 0; j < 4; ++j) {
    float s = tanhf(acc[j]);
    sbuf[(size_t)(b * H_ + h0 + j) * AF_ + f] = s;
    float v = s * aw;
#pragma unroll
    for (int off = 32; off > 0; off >>= 1) v += __shfl_down(v, off, 64);
    if (lane == 0) red[wvi][j] = v;
  }
  __syncthreads();
  if (tid < 4)
    alignv[b * H_ + h0 + tid] =
        red[0][tid] + red[1][tid] + red[2][tid] + red[3][tid] + align_b[0];
}

// ---------------- L3: softmax over H per batch. grid 16, block 128 (fast, tiny)
__global__ void k_softmax(const float* __restrict__ alignv, float* __restrict__ attn) {
  __shared__ float redm[2], reds[2];
  int b = blockIdx.x, t = threadIdx.x;
  float v = alignv[b * H_ + t];
  float m = v;
#pragma unroll
  for (int off = 32; off > 0; off >>= 1) m = fmaxf(m, __shfl_down(m, off, 64));
  if ((t & 63) == 0) redm[t >> 6] = m;
  __syncthreads();
  float mm = fmaxf(redm[0], redm[1]);
  float e = expf(v - mm);
  float s = e;
#pragma unroll
  for (int off = 32; off > 0; off >>= 1) s += __shfl_down(s, off, 64);
  if ((t & 63) == 0) reds[t >> 6] = s;
  __syncthreads();
  attn[b * H_ + t] = e / (reds[0] + reds[1]);
}

// ---------------- L4: dconv (bid<256, ~9us VALU hidden under stream) + context.
// dconv: per (b, 8 h-rows): conv K=5 pad=2 over all c + relu + maxpool4 -> dpool.
//        Reads sbuf/w2 (d_ws, L2-resident) — disjoint from ctx writes (d_out).
// ctx:   ctx[b,c,w] = sum_h feat[b,c,h,w]*attn[b,h]; nt streaming loads/store.
__global__ void k_ctx_dconv(const float* __restrict__ feat, const float* __restrict__ attn,
                            const float* __restrict__ sbuf, const float* __restrict__ w2,
                            const float* __restrict__ convd_b,
                            float* __restrict__ dpool, float* __restrict__ ctx) {
  __shared__ float sw[12][AF_];   // dconv window; ctx path reuses sw[0][0..127]
  int bidx = blockIdx.x;
  int tid = threadIdx.x;
  if (bidx < 256) {
    int b = bidx >> 4;
    int h0 = (bidx & 15) * 8;
    int f = tid;
    for (int rr = 0; rr < 12; ++rr) {          // rows h0-2 .. h0+9, zero padded
      int h = h0 - 2 + rr;
      sw[rr][f] = (h >= 0 && h < H_) ? sbuf[(size_t)(b * H_ + h) * AF_ + f] : 0.f;
    }
    __syncthreads();
    float acc[8];
#pragma unroll
    for (int j = 0; j < 8; ++j) acc[j] = 0.f;
    for (int c = 0; c < C_; ++c) {
      float sr[12];
#pragma unroll
      for (int rr = 0; rr < 12; ++rr) sr[rr] = sw[rr][c];   // LDS broadcast
      const float* wp = w2 + (size_t)c * 5 * 256 + f;
#pragma unroll
      for (int t = 0; t < 5; ++t) {
        float wvv = wp[t * 256];                            // coalesced, L2-resident
#pragma unroll
        for (int j = 0; j < 8; ++j) acc[j] = fmaf(sr[j + t], wvv, acc[j]);
      }
    }
    float bias = convd_b[f];
#pragma unroll
    for (int j = 0; j < 8; ++j) acc[j] = fmaxf(acc[j] + bias, 0.f);
    float p0 = fmaxf(fmaxf(acc[0], acc[1]), fmaxf(acc[2], acc[3]));
    float p1 = fmaxf(fmaxf(acc[4], acc[5]), fmaxf(acc[6], acc[7]));
    int m0 = h0 >> 2;
    dpool[(size_t)(b * 32 + m0) * AF_ + f] = p0;
    dpool[(size_t)(b * 32 + m0 + 1) * AF_ + f] = p1;
  } else {
    int cb = 2303 - bidx;                      // reversed traversal (cb 2047..0)
    int b = cb >> 7;
    int c0 = (cb & 127) * 2;
    float* at = &sw[0][0];
    if (tid < H_) at[tid] = attn[b * H_ + tid];
    __syncthreads();
    int c = c0 + (tid >> 7);
    int wq = tid & 127;
    const f4v* f4 = reinterpret_cast<const f4v*>(feat) +
                    (size_t)(b * C_ + c) * H_ * (W_ / 4) + wq;
    f4v acc = (f4v){0.f, 0.f, 0.f, 0.f};
#pragma unroll 4
    for (int h = 0; h < H_; ++h) {
      f4v x = __builtin_nontemporal_load(f4 + (size_t)h * (W_ / 4));
      float a = at[h];
      acc.x += x.x * a; acc.y += x.y * a; acc.z += x.z * a; acc.w += x.w * a;
    }
    __builtin_nontemporal_store(acc,
        reinterpret_cast<f4v*>(ctx) + (size_t)(b * C_ + c) * (W_ / 4) + wq);
  }
}

// ---------------- L5: dh dot + relu, concat hh, dec matmul. grid 16, block 256
__global__ void k_decision(const float* __restrict__ dpool, const float* __restrict__ hidden,
                           const float* __restrict__ dh_w, const float* __restrict__ dh_b,
                           const float* __restrict__ dec_w, const float* __restrict__ dec_b,
                           float* __restrict__ dec_out) {
  __shared__ float ddl[AF_];
  __shared__ float red[4];
  int b = blockIdx.x, tid = threadIdx.x;
  float acc = dh_b[0];
  for (int m = 0; m < 32; ++m) acc = fmaf(dpool[(size_t)(b * 32 + m) * AF_ + tid], dh_w[m], acc);
  ddl[tid] = fmaxf(acc, 0.f);
  __syncthreads();
  int col = tid >> 7, kk = tid & 127;
  float a = 0.f;
#pragma unroll
  for (int q = 0; q < 4; ++q) {
    int idx = kk + 128 * q;                  // 0..511 over concat [hh(256), dd(256)]
    float x = (idx < 256) ? hidden[b * HS_ + idx] : ddl[idx - 256];
    a = fmaf(x, dec_w[idx * 2 + col], a);
  }
#pragma unroll
  for (int off = 32; off > 0; off >>= 1) a += __shfl_down(a, off, 64);
  if ((tid & 63) == 0) red[tid >> 6] = a;
  __syncthreads();
  if (tid < 2) dec_out[b * 2 + tid] = red[tid * 2] + red[tid * 2 + 1] + dec_b[tid];
}

extern "C" void kernel_launch(void* const* d_in, const int* in_sizes, int n_in,
                              void* d_out, int out_size, void* d_ws, size_t ws_size,
                              hipStream_t stream) {
  const float* feat    = (const float*)d_in[0];
  const float* pa      = (const float*)d_in[1];
  const float* cv      = (const float*)d_in[2];
  const float* hidden  = (const float*)d_in[3];
  const float* dw_w    = (const float*)d_in[4];
  const float* dw_b    = (const float*)d_in[5];
  const float* enc_w   = (const float*)d_in[6];
  const float* enc_b   = (const float*)d_in[7];
  const float* conv_w  = (const float*)d_in[8];
  const float* conv_b  = (const float*)d_in[9];
  const float* dcb_w   = (const float*)d_in[10];
  const float* dcb_b   = (const float*)d_in[11];
  const float* hid_w   = (const float*)d_in[12];
  const float* hid_b   = (const float*)d_in[13];
  const float* align_w = (const float*)d_in[14];
  const float* align_b = (const float*)d_in[15];
  const float* convd_w = (const float*)d_in[16];
  const float* convd_b = (const float*)d_in[17];
  const float* dh_w    = (const float*)d_in[18];
  const float* dh_b    = (const float*)d_in[19];
  const float* dec_w   = (const float*)d_in[20];
  const float* dec_b   = (const float*)d_in[21];

  float* out  = (float*)d_out;
  float* ctx  = out;                          // (B,C,W) = 2,097,152 floats
  float* attn = out + 2097152;                // (B,H)   = 2048
  float* dec  = out + 2097152 + 2048;         // (B,2)   = 32

  // All scratch in d_ws (dconv reads sbuf/w2 concurrently with ctx writes in
  // L4 — must be disjoint from d_out). Every buffer fully rewritten each call
  // before it is read -> deterministic across replays.
  float* ws     = (float*)d_ws;
  float* hf     = ws;                         // 524288  h_feat (B,C,H)
  float* sbuf   = ws + 524288;                // 524288  s (B,H,AF) post-tanh
  float* hv     = ws + 1048576;               // 4096    (B,AF)
  float* alignv = ws + 1052672;               // 2048    (B,H)
  float* w2     = ws + 1054720;               // 327680  transposed convd_w
  float* dpool  = ws + 1382400;               // 131072  (B,32,AF)

  k_pre_pool<<<131344, 256, 0, stream>>>(feat, dw_w, dw_b, convd_w, hidden,
                                         hid_w, hid_b, hf, w2, hv);
  k_sbuild<<<512, 256, 0, stream>>>(pa, cv, hf, enc_w, enc_b, conv_w, conv_b,
                                    dcb_w, dcb_b, hv, align_w, align_b, sbuf, alignv);
  k_softmax<<<16, 128, 0, stream>>>(alignv, attn);
  k_ctx_dconv<<<2304, 256, 0, stream>>>(feat, attn, sbuf, w2, convd_b, dpool, ctx);
  k_decision<<<16, 256, 0, stream>>>(dpool, hidden, dh_w, dh_b, dec_w, dec_b, dec);
}